// Round 13
// baseline (28534.088 us; speedup 1.0000x reference)
//
#include <hip/hip_runtime.h>
#include <math.h>

#define NT 512
#define NB 512
#define HID 128
#define NIN 10
#define NC 10
#define CW 20
#define NIF 88
#define NOUT 10
#define GB 16         // batches per group (MFMA M)
#define BLK 512
#define NGRP 32
#define NMEM 4

// d_ws layout
#define FLAGS_BYTES 4096            // 32 groups x 16 u32 flags (slots: 0-3 h0, 4-7 xi)
#define GSTRIDE 36864               // per-group data
#define OFF_H0  0                   // 4 x 1KB A-frag slices
#define OFF_H1  4096
#define OFF_CTL 8192
#define OFF_XI  12288               // 4 members x 6 ntiles x 256 f32

typedef _Float16 h1;
typedef _Float16 h8 __attribute__((ext_vector_type(8)));
typedef float f32x4 __attribute__((ext_vector_type(4)));

__device__ __forceinline__ float rcpf(float x) { return __builtin_amdgcn_rcpf(x); }
__device__ __forceinline__ float sigf(float x) { return rcpf(1.0f + __expf(-x)); }
__device__ __forceinline__ float tanhf_(float x) {
  float xc = fminf(fmaxf(x, -15.f), 15.f);
  float e = __expf(2.f * xc);
  return (e - 1.f) * rcpf(e + 1.f);
}
__device__ __forceinline__ float splus(float x) { return fmaxf(x, 0.0f) + __logf(1.f + __expf(-fabsf(x))); }

// quad broadcast (BitMode: read (lane&0x1C)|k)
__device__ __forceinline__ float bq0(float v) { return __builtin_bit_cast(float, __builtin_amdgcn_ds_swizzle(__builtin_bit_cast(int, v), 0x001C)); }
__device__ __forceinline__ float bq1(float v) { return __builtin_bit_cast(float, __builtin_amdgcn_ds_swizzle(__builtin_bit_cast(int, v), 0x003C)); }
__device__ __forceinline__ float bq2(float v) { return __builtin_bit_cast(float, __builtin_amdgcn_ds_swizzle(__builtin_bit_cast(int, v), 0x005C)); }
__device__ __forceinline__ float bq3(float v) { return __builtin_bit_cast(float, __builtin_amdgcn_ds_swizzle(__builtin_bit_cast(int, v), 0x007C)); }

#define LDSFENCE() do { asm volatile("s_waitcnt lgkmcnt(0)" ::: "memory"); \
                        __builtin_amdgcn_sched_barrier(0); } while (0)

__device__ __forceinline__ f32x4 mfma16(float4 a, float4 b, f32x4 c) {
  return __builtin_amdgcn_mfma_f32_16x16x32_f16(
      __builtin_bit_cast(h8, a), __builtin_bit_cast(h8, b), c, 0, 0, 0);
}

__device__ __forceinline__ float4 pack8(const float* p) {
  h1 v[8];
  #pragma unroll
  for (int j = 0; j < 8; ++j) v[j] = (h1)p[j];
  return *reinterpret_cast<float4*>(v);
}

// packed row p = unit*4 + gate -> original row = gate*128 + unit
__device__ __host__ __forceinline__ int origrow(int p) { return (p & 3) * 128 + (p >> 2); }

__global__ __launch_bounds__(512) void dnc_reset_kernel(unsigned* flags) {
  int i = blockIdx.x * 512 + threadIdx.x;
  if (i < FLAGS_BYTES / 4) flags[i] = 0u;
}

__global__ __launch_bounds__(BLK)
void dnc_team_kernel(
    const float* __restrict__ x,
    const float* __restrict__ Wih0, const float* __restrict__ Whh0, const float* __restrict__ b0,
    const float* __restrict__ Wih1, const float* __restrict__ Whh1, const float* __restrict__ b1,
    const float* __restrict__ Wif,  const float* __restrict__ bif,
    const float* __restrict__ Wout, const float* __restrict__ bout,
    char* __restrict__ wsb,
    float* __restrict__ out)
{
  // ---- LDS (~148 KB) ----
  __shared__ __align__(16) float4 s_whh0[32][64];   // [w*4+kt][lane]
  __shared__ __align__(16) float4 s_wih1[32][64];
  __shared__ __align__(16) float4 s_whh1[32][64];
  __shared__ __align__(16) float4 s_wih0[8][64];    // inp-K (32) x ntile w
  __shared__ __align__(16) float4 s_wif[6][64];     // ntile x (K-slice m)
  __shared__ __align__(16) unsigned short s_ctlf[512];  // ctl A-frag (32k x 16b)
  __shared__ __align__(16) unsigned short s_inpf[512];  // inp A-frag
  __shared__ float s_mem[GB][NC][CW];
  __shared__ float s_link[GB][NC][NC];
  __shared__ float s_rk[GB][CW], s_wk[GB][CW], s_er[GB][CW], s_wv[GB][CW];
  __shared__ float s_sc[GB][8], s_mraw[GB][4];
  __shared__ float s_usage[GB][NC], s_u[GB][NC], s_prec[GB][NC], s_prec2[GB][NC];
  __shared__ float s_rw[GB][NC], s_ww[GB][NC], s_cw[GB][NC], s_cr[GB][NC];
  __shared__ float s_fwd[GB][NC], s_bwd[GB][NC];
  __shared__ float s_rv[GB][CW];
  __shared__ float s_bif[NIF];

  const int tid = threadIdx.x;
  const int l = tid & 63, w = tid >> 6;
  const int col = l & 15, g4 = l >> 4;
  const int g = blockIdx.x >> 2, m = blockIdx.x & 3;
  const int bg16 = g * GB;
  char* grp = wsb + FLAGS_BYTES + (size_t)g * GSTRIDE;
  unsigned* flags = (unsigned*)wsb + g * 16;

  // ---- weight staging (member slices; one-time) ----
  for (int idx = tid; idx < 32 * 64; idx += BLK) {
    int f = idx >> 6, ll2 = idx & 63;
    int ntg = m * 8 + (f >> 2), kt = f & 3;
    int r = origrow(ntg * 16 + (ll2 & 15));
    int k0 = kt * 32 + (ll2 >> 4) * 8;
    s_whh0[f][ll2] = pack8(Whh0 + (size_t)r * HID + k0);
    s_wih1[f][ll2] = pack8(Wih1 + (size_t)r * HID + k0);
    s_whh1[f][ll2] = pack8(Whh1 + (size_t)r * HID + k0);
  }
  for (int idx = tid; idx < 8 * 64; idx += BLK) {
    int f = idx >> 6, ll2 = idx & 63;
    int r = origrow((m * 8 + f) * 16 + (ll2 & 15));
    float tmp[8];
    #pragma unroll
    for (int j = 0; j < 8; ++j) {
      int k = (ll2 >> 4) * 8 + j;
      int cc = (k < 10) ? k : ((k < 12) ? -1 : (k - 2));
      tmp[j] = (cc < 0) ? 0.f : Wih0[r * (NIN + CW) + cc];
    }
    s_wih0[f][ll2] = pack8(tmp);
  }
  for (int idx = tid; idx < 6 * 64; idx += BLK) {
    int nt = idx >> 6, ll2 = idx & 63;
    int q = nt * 16 + (ll2 & 15);
    float tmp[8];
    #pragma unroll
    for (int j = 0; j < 8; ++j)
      tmp[j] = (q < NIF) ? Wif[q * HID + m * 32 + (ll2 >> 4) * 8 + j] : 0.f;
    s_wif[nt][ll2] = pack8(tmp);
  }
  if (tid < NIF) s_bif[tid] = bif[tid];
  // inp frag for t=0: k<10 = x(0), rest 0
  if (tid < 512) {
    int kg = tid >> 7, b = (tid >> 3) & 15, k = kg * 8 + (tid & 7);
    float v = (k < NIN) ? x[((size_t)(bg16 + b) * NT) * NIN + k] : 0.f;
    s_inpf[tid] = __builtin_bit_cast(unsigned short, (h1)v);
  }
  // zero DNC state
  for (int idx = tid; idx < GB*NC*CW; idx += BLK) { int b=idx/(NC*CW), e=idx%(NC*CW);
    s_mem[b][e/CW][e%CW] = 0.f; }
  for (int idx = tid; idx < GB*NC*NC; idx += BLK) { int b=idx/(NC*NC), e=idx%(NC*NC);
    s_link[b][e/NC][e%NC] = 0.f; }
  if (tid < GB*NC) { int b = tid & 15, n = tid >> 4;
    s_usage[b][n]=0.f; s_prec[b][n]=0.f; s_rw[b][n]=0.f; s_ww[b][n]=0.f; }
  for (int idx = tid; idx < GB*CW; idx += BLK) s_rv[idx/CW][idx%CW] = 0.f;

  // biases (per lane's packed row)
  const int prow = (m * 8 + w) * 16 + col;
  const float b0r = b0[origrow(prow)];
  const float b1r = b1[origrow(prow)];

  float c0r[4] = {0.f, 0.f, 0.f, 0.f};
  float c1r[4] = {0.f, 0.f, 0.f, 0.f};
  float4 a_h0[4], a_h1[4];
  #pragma unroll
  for (int kt = 0; kt < 4; ++kt) { a_h0[kt] = float4{0,0,0,0}; a_h1[kt] = float4{0,0,0,0}; }
  __syncthreads();

  const int kloc = w * 4 + ((l >> 2) & 3);   // local unit owned by this quad
  const int hb = l >> 5, s = l & 31;         // DNC half-wave mapping
  const int bb = 2 * w + hb;                 // DNC batch for this lane

  for (int t = 0; t < NT; ++t) {
    const unsigned want = (unsigned)(t + 1);
    // ===== S1: g0 = b0 + inp*Wih0 + h0(t-1)*Whh0 ; g1p = b1 + h1(t-1)*Whh1 =====
    float4 ainp = ((const float4*)s_inpf)[g4 * 16 + col];
    f32x4 g0 = {b0r, b0r, b0r, b0r};
    g0 = mfma16(ainp, s_wih0[w][l], g0);
    #pragma unroll
    for (int kt = 0; kt < 4; ++kt) g0 = mfma16(a_h0[kt], s_whh0[w*4+kt][l], g0);
    f32x4 g1 = {b1r, b1r, b1r, b1r};
    #pragma unroll
    for (int kt = 0; kt < 4; ++kt) g1 = mfma16(a_h1[kt], s_whh1[w*4+kt][l], g1);

    // LSTM0 + publish h0 slice
    float h0v[4];
    #pragma unroll
    for (int i = 0; i < 4; ++i) {
      float gi = bq0(g0[i]), gf = bq1(g0[i]), gg = bq2(g0[i]), go = bq3(g0[i]);
      float c = sigf(gf) * c0r[i] + sigf(gi) * tanhf_(gg);
      c0r[i] = c;
      h0v[i] = sigf(go) * tanhf_(c);
    }
    if ((l & 3) == 0) {
      unsigned short* dst = (unsigned short*)(grp + OFF_H0 + m * 1024);
      #pragma unroll
      for (int i = 0; i < 4; ++i) {
        int b = g4 * 4 + i;
        dst[((kloc >> 3) * 16 + b) * 8 + (kloc & 7)] =
            __builtin_bit_cast(unsigned short, (h1)h0v[i]);
      }
    }
    __syncthreads();                                       // B1: h0 stores drained
    if (tid == 0) {
      __threadfence();
      __hip_atomic_store(&flags[m], want, __ATOMIC_RELEASE, __HIP_MEMORY_SCOPE_AGENT);
    }
    // W1: wait all h0 slices
    #pragma unroll
    for (int mm = 0; mm < 4; ++mm) {
      int spin = 0;
      while (__hip_atomic_load(&flags[mm], __ATOMIC_RELAXED, __HIP_MEMORY_SCOPE_AGENT) < want
             && spin < (1 << 26)) { __builtin_amdgcn_s_sleep(2); ++spin; }
    }
    __threadfence();

    // ===== S2: g1 += h0(t)*Wih1 ; LSTM1 =====
    #pragma unroll
    for (int kt = 0; kt < 4; ++kt)
      a_h0[kt] = *(const float4*)(grp + OFF_H0 + kt * 1024 + l * 16);
    #pragma unroll
    for (int kt = 0; kt < 4; ++kt) g1 = mfma16(a_h0[kt], s_wih1[w*4+kt][l], g1);

    float h1v[4], clv[4];
    #pragma unroll
    for (int i = 0; i < 4; ++i) {
      float gi = bq0(g1[i]), gf = bq1(g1[i]), gg = bq2(g1[i]), go = bq3(g1[i]);
      float c = sigf(gf) * c1r[i] + sigf(gi) * tanhf_(gg);
      c1r[i] = c;
      float h = sigf(go) * tanhf_(c);
      h1v[i] = h;
      clv[i] = fminf(fmaxf(h, -20.f), 20.f);
    }
    if ((l & 3) == 0) {
      unsigned short* dh = (unsigned short*)(grp + OFF_H1 + m * 1024);
      unsigned short* dc = (unsigned short*)(grp + OFF_CTL + m * 1024);
      #pragma unroll
      for (int i = 0; i < 4; ++i) {
        int b = g4 * 4 + i;
        int off = ((kloc >> 3) * 16 + b) * 8 + (kloc & 7);
        dh[off] = __builtin_bit_cast(unsigned short, (h1)h1v[i]);
        s_ctlf[off] = __builtin_bit_cast(unsigned short, (h1)clv[i]);
        if (t == NT - 1) dc[off] = __builtin_bit_cast(unsigned short, (h1)clv[i]);
      }
    }
    __syncthreads();                                       // B2: ctlf + h1/ctl stores

    // ===== xi K-partial: (ctl slice) x (Wif K-slice) =====
    if (w < 6) {
      float4 actl = ((const float4*)s_ctlf)[g4 * 16 + col];
      f32x4 xa = {0.f, 0.f, 0.f, 0.f};
      xa = mfma16(actl, s_wif[w][l], xa);
      float* xd = (float*)(grp + OFF_XI + (m * 6 + w) * 1024);
      #pragma unroll
      for (int i = 0; i < 4; ++i) xd[(g4 * 4 + i) * 16 + col] = xa[i];
    }
    __syncthreads();                                       // B3: xi stores drained
    if (tid == 0) {
      __threadfence();
      __hip_atomic_store(&flags[4 + m], want, __ATOMIC_RELEASE, __HIP_MEMORY_SCOPE_AGENT);
    }
    // x(t+1) prefetch (hide under spin)
    float xv = 0.f;
    if (s < NIN && (t + 1) < NT)
      xv = x[((size_t)(bg16 + bb) * NT + (t + 1)) * NIN + s];
    // W3: wait all xi partials (also guarantees h1 slices)
    #pragma unroll
    for (int mm = 0; mm < 4; ++mm) {
      int spin = 0;
      while (__hip_atomic_load(&flags[4 + mm], __ATOMIC_RELAXED, __HIP_MEMORY_SCOPE_AGENT) < want
             && spin < (1 << 26)) { __builtin_amdgcn_s_sleep(2); ++spin; }
    }
    __threadfence();
    #pragma unroll
    for (int kt = 0; kt < 4; ++kt)
      a_h1[kt] = *(const float4*)(grp + OFF_H1 + kt * 1024 + l * 16);

    // ===== replicated DNC: wave w owns batches 2w, 2w+1 (wave-local, fences) =====
    // sum xi partials + transforms
    #pragma unroll
    for (int r = 0; r < 3; ++r) {
      int q = s + r * 32;
      if (q < NIF) {
        float a = s_bif[q];
        #pragma unroll
        for (int mm = 0; mm < 4; ++mm)
          a += *(const float*)(grp + OFF_XI + (mm * 6 + (q >> 4)) * 1024 + (bb * 16 + (q & 15)) * 4);
        if      (q < 20)  s_rk[bb][q]    = tanhf_(a);
        else if (q == 20) s_sc[bb][0]    = splus(a);
        else if (q < 41)  s_wk[bb][q-21] = tanhf_(a);
        else if (q == 41) s_sc[bb][1]    = splus(a);
        else if (q < 62)  s_er[bb][q-42] = sigf(a);
        else if (q < 82)  s_wv[bb][q-62] = tanhf_(a);
        else if (q == 82) s_sc[bb][2]    = sigf(a);
        else if (q == 83) s_sc[bb][3]    = sigf(a);
        else if (q == 84) s_sc[bb][4]    = sigf(a);
        else              s_mraw[bb][q-85] = a;
      }
    }
    LDSFENCE();
    // H
    if (s < NC) {
      int n = s;
      float fg = s_sc[bb][2];
      float psi = 1.f - fg * s_rw[bb][n];
      float u = s_usage[bb][n], wq = s_ww[bb][n];
      u = (u + wq - u * wq) * psi;
      s_usage[bb][n] = u;
      s_u[bb][n] = 1e-6f + (1.0f - 1e-6f) * u;
      float dot = 0.f, mn = 0.f, kn = 0.f;
      #pragma unroll
      for (int c = 0; c < CW; ++c) {
        float mv = s_mem[bb][n][c], kv = s_wk[bb][c];
        dot += kv * mv; mn += mv * mv; kn += kv * kv;
      }
      s_cw[bb][n] = dot * rcpf(sqrtf(kn) * sqrtf(mn) + 1e-6f) * s_sc[bb][1];
    } else if (s == NC) {
      float m0 = s_mraw[bb][0], m1 = s_mraw[bb][1], m2 = s_mraw[bb][2];
      float mm2 = fmaxf(m0, fmaxf(m1, m2));
      float e0 = __expf(m0 - mm2), e1 = __expf(m1 - mm2), e2 = __expf(m2 - mm2);
      float es = rcpf(e0 + e1 + e2);
      s_sc[bb][5] = e0 * es; s_sc[bb][6] = e1 * es; s_sc[bb][7] = e2 * es;
    }
    LDSFENCE();
    // I
    if (s < NC) {
      int n = s;
      float mx = -1e30f;
      #pragma unroll
      for (int mm = 0; mm < NC; ++mm) mx = fmaxf(mx, s_cw[bb][mm]);
      float sm = 0.f;
      #pragma unroll
      for (int mm = 0; mm < NC; ++mm) sm += __expf(s_cw[bb][mm] - mx);
      float cwv = __expf(s_cw[bb][n] - mx) * rcpf(sm);
      float un = s_u[bb][n];
      float excl = 1.f;
      #pragma unroll
      for (int mm = 0; mm < NC; ++mm) {
        float um = s_u[bb][mm];
        bool before = (um < un) || (um == un && mm < n);
        excl *= before ? um : 1.f;
      }
      float alloc = (1.f - un) * excl;
      float ga = s_sc[bb][3], gw = s_sc[bb][4];
      s_ww[bb][n] = gw * (ga * alloc + (1.f - ga) * cwv);
    }
    LDSFENCE();
    // J
    #pragma unroll
    for (int e = s; e < NC * CW; e += 32) {
      int rr = e / CW, c = e % CW;
      float wq = s_ww[bb][rr];
      s_mem[bb][rr][c] = s_mem[bb][rr][c] * (1.f - wq * s_er[bb][c]) + wq * s_wv[bb][c];
    }
    #pragma unroll
    for (int e = s; e < NC * NC; e += 32) {
      int i2 = e / NC, j2 = e % NC;
      float wi = s_ww[bb][i2], wj = s_ww[bb][j2];
      float ln = (1.f - wi - wj) * s_link[bb][i2][j2] + wi * s_prec[bb][j2];
      s_link[bb][i2][j2] = (i2 == j2) ? 0.f : ln;
    }
    if (s < NC) {
      float sw2 = 0.f;
      #pragma unroll
      for (int mm = 0; mm < NC; ++mm) sw2 += s_ww[bb][mm];
      s_prec2[bb][s] = (1.f - sw2) * s_prec[bb][s] + s_ww[bb][s];
    }
    LDSFENCE();
    // K
    if (s < NC) {
      int mm2 = s;
      s_prec[bb][mm2] = s_prec2[bb][mm2];
      float a = 0.f;
      #pragma unroll
      for (int n = 0; n < NC; ++n) a += s_rw[bb][n] * s_link[bb][mm2][n];
      s_fwd[bb][mm2] = a;
    } else if (s < 2 * NC) {
      int mm2 = s - NC;
      float a = 0.f;
      #pragma unroll
      for (int n = 0; n < NC; ++n) a += s_rw[bb][n] * s_link[bb][n][mm2];
      s_bwd[bb][mm2] = a;
    } else if (s < 3 * NC) {
      int n = s - 2 * NC;
      float dot = 0.f, mn = 0.f, kn = 0.f;
      #pragma unroll
      for (int c = 0; c < CW; ++c) {
        float mv = s_mem[bb][n][c], kv = s_rk[bb][c];
        dot += kv * mv; mn += mv * mv; kn += kv * kv;
      }
      s_cr[bb][n] = dot * rcpf(sqrtf(kn) * sqrtf(mn) + 1e-6f) * s_sc[bb][0];
    }
    LDSFENCE();
    // L
    if (s < NC) {
      int n = s;
      float mx = -1e30f;
      #pragma unroll
      for (int mm = 0; mm < NC; ++mm) mx = fmaxf(mx, s_cr[bb][mm]);
      float sm = 0.f;
      #pragma unroll
      for (int mm = 0; mm < NC; ++mm) sm += __expf(s_cr[bb][mm] - mx);
      float cr = __expf(s_cr[bb][n] - mx) * rcpf(sm);
      s_rw[bb][n] = s_sc[bb][5] * s_bwd[bb][n] + s_sc[bb][6] * cr + s_sc[bb][7] * s_fwd[bb][n];
    }
    LDSFENCE();
    // M: rv -> inpf (k=12+c); x(t+1) -> inpf (k<10)
    if (s < CW) {
      float a = 0.f;
      #pragma unroll
      for (int n = 0; n < NC; ++n) a += s_rw[bb][n] * s_mem[bb][n][s];
      s_rv[bb][s] = a;
      int k = 12 + s;
      s_inpf[((k >> 3) * 16 + bb) * 8 + (k & 7)] = __builtin_bit_cast(unsigned short, (h1)a);
    }
    if (s < NIN && (t + 1) < NT)
      s_inpf[((s >> 3) * 16 + bb) * 8 + (s & 7)] = __builtin_bit_cast(unsigned short, (h1)xv);
    __syncthreads();                                       // B4: inpf ready
  }

  // ---- epilogue (member 0): y = [ctrl, rv] @ Wout^T + bout ----
  if (m == 0 && tid < GB * NOUT) {
    int b = tid / NOUT, o = tid % NOUT;
    float a = bout[o];
    const float* Wr = Wout + o * (HID + CW);
    const unsigned short* ctl = (const unsigned short*)(grp + OFF_CTL);
    #pragma unroll 4
    for (int k = 0; k < HID; ++k) {
      int mk = k >> 5, kl = k & 31;
      unsigned short uv = ctl[mk * 512 + ((kl >> 3) * 16 + b) * 8 + (kl & 7)];
      a += Wr[k] * (float)__builtin_bit_cast(h1, uv);
    }
    #pragma unroll
    for (int c = 0; c < CW; ++c) a += Wr[HID + c] * s_rv[b][c];
    out[(size_t)(bg16 + b) * NOUT + o] = a;
  }
}

extern "C" void kernel_launch(void* const* d_in, const int* in_sizes, int n_in,
                              void* d_out, int out_size, void* d_ws, size_t ws_size,
                              hipStream_t stream) {
  (void)in_sizes; (void)n_in; (void)out_size; (void)ws_size;
  const float* x    = (const float*)d_in[0];
  const float* Wih0 = (const float*)d_in[1];
  const float* Whh0 = (const float*)d_in[2];
  const float* b0   = (const float*)d_in[3];
  const float* Wih1 = (const float*)d_in[4];
  const float* Whh1 = (const float*)d_in[5];
  const float* b1   = (const float*)d_in[6];
  const float* Wif  = (const float*)d_in[7];
  const float* bif  = (const float*)d_in[8];
  const float* Wout = (const float*)d_in[9];
  const float* bout = (const float*)d_in[10];
  float* out = (float*)d_out;
  char* ws = (char*)d_ws;

  dnc_reset_kernel<<<dim3(2), dim3(512), 0, stream>>>((unsigned*)ws);
  dnc_team_kernel<<<dim3(NGRP * NMEM), dim3(BLK), 0, stream>>>(
      x, Wih0, Whh0, b0, Wih1, Whh1, b1, Wif, bif, Wout, bout, ws, out);
}

// Round 15
// 5314.442 us; speedup vs baseline: 5.3692x; 5.3692x over previous
//
#include <hip/hip_runtime.h>
#include <math.h>

#define NT 512
#define NB 512
#define HID 128
#define NIN 10
#define NC 10
#define CW 20
#define NIF 88
#define NOUT 10
#define GB 16         // batches per workgroup = MFMA M dim
#define BLK 512       // 8 waves
#define NWG (NB/GB)   // 32 workgroups

typedef _Float16 h1;
typedef _Float16 h8 __attribute__((ext_vector_type(8)));
typedef float f32x4 __attribute__((ext_vector_type(4)));

__device__ __forceinline__ float rcpf(float x) { return __builtin_amdgcn_rcpf(x); }
__device__ __forceinline__ float sigf(float x) { return rcpf(1.0f + __expf(-x)); }
__device__ __forceinline__ float tanhf_(float x) {
  float xc = fminf(fmaxf(x, -15.f), 15.f);
  float e = __expf(2.f * xc);
  return (e - 1.f) * rcpf(e + 1.f);
}
__device__ __forceinline__ float splus(float x) { return fmaxf(x, 0.0f) + __logf(1.f + __expf(-fabsf(x))); }

// quad broadcast (BitMode: read (lane&0x1C)|k)
__device__ __forceinline__ float bq0(float v) { return __builtin_bit_cast(float, __builtin_amdgcn_ds_swizzle(__builtin_bit_cast(int, v), 0x001C)); }
__device__ __forceinline__ float bq1(float v) { return __builtin_bit_cast(float, __builtin_amdgcn_ds_swizzle(__builtin_bit_cast(int, v), 0x003C)); }
__device__ __forceinline__ float bq2(float v) { return __builtin_bit_cast(float, __builtin_amdgcn_ds_swizzle(__builtin_bit_cast(int, v), 0x005C)); }
__device__ __forceinline__ float bq3(float v) { return __builtin_bit_cast(float, __builtin_amdgcn_ds_swizzle(__builtin_bit_cast(int, v), 0x007C)); }

#define LDSFENCE() do { asm volatile("s_waitcnt lgkmcnt(0)" ::: "memory"); \
                        __builtin_amdgcn_sched_barrier(0); } while (0)

__device__ __forceinline__ f32x4 mfma16(float4 a, float4 b, f32x4 c) {
  return __builtin_amdgcn_mfma_f32_16x16x32_f16(
      __builtin_bit_cast(h8, a), __builtin_bit_cast(h8, b), c, 0, 0, 0);
}

__device__ __forceinline__ float4 pack8(const float* p) {
  h1 v[8];
  #pragma unroll
  for (int j = 0; j < 8; ++j) v[j] = (h1)p[j];
  return *reinterpret_cast<float4*>(v);
}

// packed row prow = unit*4 + gate  ->  original row = gate*128 + unit
__device__ __host__ __forceinline__ int origrow(int prow) { return (prow & 3) * 128 + (prow >> 2); }

// ---- pack kernel (identical layout to r12): fragment-ordered fp16 weights ----
// frag 0..127: Whh0 ; 128..255: Wih1 ; 256..383: Whh1 ;  f = nt*4+kt
__global__ __launch_bounds__(256) void dnc_packf_kernel(
    const float* __restrict__ Whh0, const float* __restrict__ Wih1,
    const float* __restrict__ Whh1, float4* __restrict__ ws)
{
  int i = blockIdx.x * 256 + threadIdx.x;
  if (i >= 384 * 64) return;
  int l = i & 63, frag = i >> 6;
  int m = frag >> 7, f = frag & 127;
  int nt = f >> 2, kt = f & 3;
  int r = origrow(nt * 16 + (l & 15));
  int k0 = kt * 32 + (l >> 4) * 8;
  const float* W = (m == 0) ? Whh0 : (m == 1) ? Wih1 : Whh1;
  ws[i] = pack8(W + (size_t)r * HID + k0);
}

__global__ __launch_bounds__(BLK)
void dnc_olap2_kernel(
    const float* __restrict__ x,
    const float* __restrict__ Wih0, const float* __restrict__ Whh0, const float* __restrict__ b0,
    const float* __restrict__ Wih1, const float* __restrict__ Whh1, const float* __restrict__ b1,
    const float* __restrict__ Wif,  const float* __restrict__ bif,
    const float* __restrict__ Wout, const float* __restrict__ bout,
    const float4* __restrict__ wsT,
    float* __restrict__ out)
{
  __shared__ __align__(16) float4 s_w0f[32*64];     // Wih0 frags
  __shared__ __align__(16) float4 s_wiff[24*64];    // Wif frags
  __shared__ __align__(16) h1 s_h0f[16*16*8];       // fragments [kg][b][8]
  __shared__ __align__(16) h1 s_h1f[16*16*8];
  __shared__ __align__(16) h1 s_ctf[16*16*8];
  __shared__ __align__(16) h1 s_inpf[4*16*8];
  __shared__ float s_c0[GB][HID], s_c1[GB][HID];
  __shared__ float s_ctrl32[GB][HID];
  __shared__ float s_mem[GB][NC][CW];
  __shared__ float s_link[GB][NC][NC];
  __shared__ float s_rk[GB][CW], s_wk[GB][CW], s_er[GB][CW], s_wv[GB][CW];
  __shared__ float s_sc[GB][8], s_mraw[GB][4];
  __shared__ float s_usage[GB][NC], s_u[GB][NC], s_prec[GB][NC], s_prec2[GB][NC];
  __shared__ float s_rw[GB][NC], s_ww[GB][NC], s_cw[GB][NC], s_cr[GB][NC];
  __shared__ float s_fwd[GB][NC], s_bwd[GB][NC];
  __shared__ float s_rv[GB][CW];

  const int tid = threadIdx.x;
  const int l = tid & 63, w = tid >> 6;
  const int col = l & 15, g4 = l >> 4, q4 = l & 3;
  const int bbase = blockIdx.x * GB;
  const int s = l & 31, bb = 2 * w + (l >> 5);   // wave-local DNC mapping

  // ---- init (identical to r12) ----
  for (int idx = tid; idx < 32*64; idx += BLK) {
    int nt = idx >> 6, ll = idx & 63;
    int r = origrow(nt*16 + (ll & 15));
    int kg = ll >> 4;
    float tmp[8];
    #pragma unroll
    for (int j = 0; j < 8; ++j) {
      int k = kg*8 + j;
      int cc = (k < 10) ? k : ((k < 12) ? -1 : (k - 2));
      tmp[j] = (cc < 0) ? 0.f : Wih0[r*(NIN+CW) + cc];
    }
    s_w0f[idx] = pack8(tmp);
  }
  for (int idx = tid; idx < 24*64; idx += BLK) {
    int f = idx >> 6, ll = idx & 63;
    int nt = f >> 2, kt = f & 3;
    int q = nt*16 + (ll & 15);
    int k0 = kt*32 + (ll >> 4)*8;
    float tmp[8];
    #pragma unroll
    for (int j = 0; j < 8; ++j) tmp[j] = (q < NIF) ? Wif[q*HID + k0 + j] : 0.f;
    s_wiff[idx] = pack8(tmp);
  }
  for (int idx = tid; idx < 16*16*8; idx += BLK) {
    s_h0f[idx] = (h1)0.f; s_h1f[idx] = (h1)0.f; s_ctf[idx] = (h1)0.f;
  }
  if (tid < 4*16*8) s_inpf[tid] = (h1)0.f;
  for (int idx = tid; idx < GB*HID; idx += BLK) { int b = idx >> 7, u = idx & 127;
    s_c0[b][u] = 0.f; s_c1[b][u] = 0.f; s_ctrl32[b][u] = 0.f; }
  for (int idx = tid; idx < GB*NC*CW; idx += BLK) { int b = idx/(NC*CW), e = idx%(NC*CW);
    s_mem[b][e/CW][e%CW] = 0.f; }
  for (int idx = tid; idx < GB*NC*NC; idx += BLK) { int b = idx/(NC*NC), e = idx%(NC*NC);
    s_link[b][e/NC][e%NC] = 0.f; }
  if (tid < GB*NC) { int b = tid & 15, n = tid >> 4;
    s_usage[b][n] = 0.f; s_prec[b][n] = 0.f; s_rw[b][n] = 0.f; s_ww[b][n] = 0.f; }
  for (int idx = tid; idx < GB*CW; idx += BLK) { int b = idx/CW, c = idx%CW; s_rv[b][c] = 0.f; }
  if (tid < GB*NIN) { int b = tid/NIN, i = tid - b*NIN;
    float v = x[((size_t)(bbase+b)*NT + 0)*NIN + i];
    s_inpf[((i>>3)*16 + b)*8 + (i&7)] = (h1)v;
  }
  const float b0v0 = b0[origrow((w*4+0)*16+col)], b0v1 = b0[origrow((w*4+1)*16+col)];
  const float b0v2 = b0[origrow((w*4+2)*16+col)], b0v3 = b0[origrow((w*4+3)*16+col)];
  const float b1v0 = b1[origrow((w*4+0)*16+col)], b1v1 = b1[origrow((w*4+1)*16+col)];
  const float b1v2 = b1[origrow((w*4+2)*16+col)], b1v3 = b1[origrow((w*4+3)*16+col)];
  float bifv = 0.f;
  if (w < 6) { int q = w*16 + col; bifv = (q < NIF) ? bif[q] : 0.f; }
  __syncthreads();

  const float4* h0fp = (const float4*)s_h0f;
  const float4* h1fp = (const float4*)s_h1f;
  const float4* ctfp = (const float4*)s_ctf;
  const float4* inpfp = (const float4*)s_inpf;

  // ---- wave-local DNC phases (wave w owns batches 2w, 2w+1; lanes s=l&31) ----
  auto dncH = [&]() {
    if (s < NC) {
      int n = s;
      float fg = s_sc[bb][2];
      float psi = 1.f - fg * s_rw[bb][n];
      float u = s_usage[bb][n], wq = s_ww[bb][n];
      u = (u + wq - u*wq) * psi;
      s_usage[bb][n] = u;
      s_u[bb][n] = 1e-6f + (1.0f - 1e-6f) * u;
      float dot = 0.f, mn = 0.f, kn = 0.f;
      #pragma unroll
      for (int c = 0; c < CW; ++c) {
        float mv = s_mem[bb][n][c], kv = s_wk[bb][c];
        dot += kv*mv; mn += mv*mv; kn += kv*kv;
      }
      s_cw[bb][n] = dot * rcpf(sqrtf(kn)*sqrtf(mn) + 1e-6f) * s_sc[bb][1];
    } else if (s == NC) {
      float m0 = s_mraw[bb][0], m1 = s_mraw[bb][1], m2 = s_mraw[bb][2];
      float mm = fmaxf(m0, fmaxf(m1, m2));
      float e0 = __expf(m0-mm), e1 = __expf(m1-mm), e2 = __expf(m2-mm);
      float es = rcpf(e0+e1+e2);
      s_sc[bb][5] = e0*es; s_sc[bb][6] = e1*es; s_sc[bb][7] = e2*es;
    }
  };
  auto dncI = [&]() {
    if (s < NC) {
      int n = s;
      float mx = -1e30f;
      #pragma unroll
      for (int m = 0; m < NC; ++m) mx = fmaxf(mx, s_cw[bb][m]);
      float sm = 0.f;
      #pragma unroll
      for (int m = 0; m < NC; ++m) sm += __expf(s_cw[bb][m]-mx);
      float cwv = __expf(s_cw[bb][n]-mx) * rcpf(sm);
      float un = s_u[bb][n];
      float excl = 1.f;
      #pragma unroll
      for (int m = 0; m < NC; ++m) {
        float um = s_u[bb][m];
        bool before = (um < un) || (um == un && m < n);
        excl *= before ? um : 1.f;
      }
      float alloc = (1.f - un) * excl;
      float ga = s_sc[bb][3], gw = s_sc[bb][4];
      s_ww[bb][n] = gw * (ga*alloc + (1.f-ga)*cwv);
    }
  };
  auto dncJ = [&]() {
    #pragma unroll
    for (int e = s; e < NC*CW; e += 32) {
      int rr = e/CW, c = e%CW;
      float wq = s_ww[bb][rr];
      s_mem[bb][rr][c] = s_mem[bb][rr][c]*(1.f - wq*s_er[bb][c]) + wq*s_wv[bb][c];
    }
    #pragma unroll
    for (int e = s; e < NC*NC; e += 32) {
      int i2 = e/NC, j2 = e%NC;
      float wi = s_ww[bb][i2], wj = s_ww[bb][j2];
      float ln = (1.f - wi - wj)*s_link[bb][i2][j2] + wi*s_prec[bb][j2];
      s_link[bb][i2][j2] = (i2==j2) ? 0.f : ln;
    }
    if (s < NC) {
      float sw2 = 0.f;
      #pragma unroll
      for (int m = 0; m < NC; ++m) sw2 += s_ww[bb][m];
      s_prec2[bb][s] = (1.f - sw2)*s_prec[bb][s] + s_ww[bb][s];
    }
  };
  auto dncK = [&]() {
    if (s < NC) {
      int m = s;
      s_prec[bb][m] = s_prec2[bb][m];
      float a = 0.f;
      #pragma unroll
      for (int n = 0; n < NC; ++n) a += s_rw[bb][n]*s_link[bb][m][n];
      s_fwd[bb][m] = a;
    } else if (s < 2*NC) {
      int m = s - NC;
      float a = 0.f;
      #pragma unroll
      for (int n = 0; n < NC; ++n) a += s_rw[bb][n]*s_link[bb][n][m];
      s_bwd[bb][m] = a;
    } else if (s < 3*NC) {
      int n = s - 2*NC;
      float dot = 0.f, mn = 0.f, kn = 0.f;
      #pragma unroll
      for (int c = 0; c < CW; ++c) {
        float mv = s_mem[bb][n][c], kv = s_rk[bb][c];
        dot += kv*mv; mn += mv*mv; kn += kv*kv;
      }
      s_cr[bb][n] = dot * rcpf(sqrtf(kn)*sqrtf(mn) + 1e-6f) * s_sc[bb][0];
    }
  };
  auto dncL = [&]() {
    if (s < NC) {
      int n = s;
      float mx = -1e30f;
      #pragma unroll
      for (int m = 0; m < NC; ++m) mx = fmaxf(mx, s_cr[bb][m]);
      float sm = 0.f;
      #pragma unroll
      for (int m = 0; m < NC; ++m) sm += __expf(s_cr[bb][m]-mx);
      float cr = __expf(s_cr[bb][n]-mx)*rcpf(sm);
      s_rw[bb][n] = s_sc[bb][5]*s_bwd[bb][n] + s_sc[bb][6]*cr + s_sc[bb][7]*s_fwd[bb][n];
    }
  };
  auto dncM = [&]() {
    if (s < CW) {
      float a = 0.f;
      #pragma unroll
      for (int n = 0; n < NC; ++n) a += s_rw[bb][n]*s_mem[bb][n][s];
      s_rv[bb][s] = a;
      int k = 12 + s;
      s_inpf[((k>>3)*16 + bb)*8 + (k&7)] = (h1)a;
    }
  };

  // ---- LSTM layer (identical to r12) ----
  auto lstm_layer = [&](f32x4 ac0, f32x4 ac1, f32x4 ac2, f32x4 ac3,
                        float (*cst)[HID], h1* hf, bool isL1) {
    float GI[4] = {0,0,0,0}, GF[4] = {0,0,0,0}, GG[4] = {0,0,0,0}, GO[4] = {0,0,0,0};
    #pragma unroll
    for (int r = 0; r < 4; ++r) {
      f32x4 A = (r==0) ? ac0 : (r==1) ? ac1 : (r==2) ? ac2 : ac3;
      #pragma unroll
      for (int i = 0; i < 4; ++i) {
        float t0 = bq0(A[i]), t1 = bq1(A[i]), t2 = bq2(A[i]), t3 = bq3(A[i]);
        GI[i] = (q4 == r) ? t0 : GI[i];
        GF[i] = (q4 == r) ? t1 : GF[i];
        GG[i] = (q4 == r) ? t2 : GG[i];
        GO[i] = (q4 == r) ? t3 : GO[i];
      }
    }
    const int u = (w*4 + q4)*4 + (col >> 2);
    #pragma unroll
    for (int i = 0; i < 4; ++i) {
      int b = g4*4 + i;
      float c = sigf(GF[i])*cst[b][u] + sigf(GI[i])*tanhf_(GG[i]);
      cst[b][u] = c;
      float h = sigf(GO[i])*tanhf_(c);
      hf[((u>>3)*16 + b)*8 + (u&7)] = (h1)h;
      if (isL1) {
        float cl = fminf(fmaxf(h, -20.f), 20.f);
        s_ctf[((u>>3)*16 + b)*8 + (u&7)] = (h1)cl;
        s_ctrl32[b][u] = cl;
      }
    }
  };

#define LDG(B0,B1,B2,B3, FB) { B0 = WS[((FB)+0)*64+l]; B1 = WS[((FB)+1)*64+l]; \
                               B2 = WS[((FB)+2)*64+l]; B3 = WS[((FB)+3)*64+l]; }
#define MMAH0(ACC,B0,B1,B2,B3) { \
  { float4 a_ = h0fp[(0*4+g4)*16+col]; ACC = mfma16(a_, B0, ACC); } \
  { float4 a_ = h0fp[(1*4+g4)*16+col]; ACC = mfma16(a_, B1, ACC); } \
  { float4 a_ = h0fp[(2*4+g4)*16+col]; ACC = mfma16(a_, B2, ACC); } \
  { float4 a_ = h0fp[(3*4+g4)*16+col]; ACC = mfma16(a_, B3, ACC); } }
#define MMAH1(ACC,B0,B1,B2,B3) { \
  { float4 a_ = h1fp[(0*4+g4)*16+col]; ACC = mfma16(a_, B0, ACC); } \
  { float4 a_ = h1fp[(1*4+g4)*16+col]; ACC = mfma16(a_, B1, ACC); } \
  { float4 a_ = h1fp[(2*4+g4)*16+col]; ACC = mfma16(a_, B2, ACC); } \
  { float4 a_ = h1fp[(3*4+g4)*16+col]; ACC = mfma16(a_, B3, ACC); } }

  for (int t = 0; t < NT; ++t) {
    unsigned lnd = 0;
    asm volatile("" : "+v"(lnd));   // defeat LICM of loop-invariant WS loads
    const float4* WS = (const float4*)((const char*)wsT + lnd);

    // ===== R1: DNC(t-1) (wave-local fences) interleaved with Whh0/Whh1 stream =====
    // frag bases: Whh0 = 0, Wih1 = 128, Whh1 = 256  (FIX: was 128*4/256*4 in r14)
    f32x4 g00 = {b0v0,b0v0,b0v0,b0v0}, g01 = {b0v1,b0v1,b0v1,b0v1};
    f32x4 g02 = {b0v2,b0v2,b0v2,b0v2}, g03 = {b0v3,b0v3,b0v3,b0v3};
    f32x4 g10 = {b1v0,b1v0,b1v0,b1v0}, g11 = {b1v1,b1v1,b1v1,b1v1};
    f32x4 g12 = {b1v2,b1v2,b1v2,b1v2}, g13 = {b1v3,b1v3,b1v3,b1v3};
    float4 P0,P1,P2,P3, Q0,Q1,Q2,Q3;
    LDG(P0,P1,P2,P3, (w*4+0)*4)
    LDG(Q0,Q1,Q2,Q3, (w*4+1)*4)
    if (t > 0) dncH();
    LDSFENCE();
    MMAH0(g00, P0,P1,P2,P3)
    LDG(P0,P1,P2,P3, (w*4+2)*4)
    if (t > 0) dncI();
    LDSFENCE();
    MMAH0(g01, Q0,Q1,Q2,Q3)
    LDG(Q0,Q1,Q2,Q3, (w*4+3)*4)
    if (t > 0) dncJ();
    LDSFENCE();
    MMAH0(g02, P0,P1,P2,P3)
    LDG(P0,P1,P2,P3, 256 + (w*4+0)*4)
    if (t > 0) dncK();
    LDSFENCE();
    MMAH0(g03, Q0,Q1,Q2,Q3)
    LDG(Q0,Q1,Q2,Q3, 256 + (w*4+1)*4)
    if (t > 0) dncL();
    LDSFENCE();
    MMAH1(g10, P0,P1,P2,P3)
    LDG(P0,P1,P2,P3, 256 + (w*4+2)*4)
    if (t > 0) dncM();
    LDSFENCE();
    MMAH1(g11, Q0,Q1,Q2,Q3)
    LDG(Q0,Q1,Q2,Q3, 256 + (w*4+3)*4)
    MMAH1(g12, P0,P1,P2,P3)
    MMAH1(g13, Q0,Q1,Q2,Q3)
    __syncthreads();   // B1: DNC done (inpf rv), all h-frag reads done

    // ===== R2: g0 += inp*Wih0 ; LSTM0 -> h0f =====
    {
      float4 ainp = inpfp[g4*16 + col];
      g00 = mfma16(ainp, s_w0f[(w*4+0)*64 + l], g00);
      g01 = mfma16(ainp, s_w0f[(w*4+1)*64 + l], g01);
      g02 = mfma16(ainp, s_w0f[(w*4+2)*64 + l], g02);
      g03 = mfma16(ainp, s_w0f[(w*4+3)*64 + l], g03);
      lstm_layer(g00, g01, g02, g03, s_c0, s_h0f, false);
    }
    __syncthreads();   // B2: h0f(t) visible

    // ===== R3: g1 += Wih1*h0(t) ; LSTM1 -> h1f/ctf =====
    LDG(P0,P1,P2,P3, 128 + (w*4+0)*4)
    LDG(Q0,Q1,Q2,Q3, 128 + (w*4+1)*4)
    MMAH0(g10, P0,P1,P2,P3)
    LDG(P0,P1,P2,P3, 128 + (w*4+2)*4)
    MMAH0(g11, Q0,Q1,Q2,Q3)
    LDG(Q0,Q1,Q2,Q3, 128 + (w*4+3)*4)
    MMAH0(g12, P0,P1,P2,P3)
    MMAH0(g13, Q0,Q1,Q2,Q3)
    lstm_layer(g10, g11, g12, g13, s_c1, s_h1f, true);
    __syncthreads();   // B3: h1f/ctf/ctrl32 visible

    // ===== R4: xi GEMM + transforms (waves 0-5) | x(t+1) prefetch (waves 6-7) =====
    if (w < 6) {
      float4 ac0 = ctfp[(0*4+g4)*16 + col], ac1 = ctfp[(1*4+g4)*16 + col];
      float4 ac2 = ctfp[(2*4+g4)*16 + col], ac3 = ctfp[(3*4+g4)*16 + col];
      f32x4 acc = {bifv, bifv, bifv, bifv};
      acc = mfma16(ac0, s_wiff[(w*4+0)*64 + l], acc);
      acc = mfma16(ac1, s_wiff[(w*4+1)*64 + l], acc);
      acc = mfma16(ac2, s_wiff[(w*4+2)*64 + l], acc);
      acc = mfma16(ac3, s_wiff[(w*4+3)*64 + l], acc);
      int q = w*16 + col;
      if (q < NIF) {
        #pragma unroll
        for (int i = 0; i < 4; ++i) {
          float a = acc[i];
          int b = g4*4 + i;
          if      (q < 20)  s_rk[b][q]    = tanhf_(a);
          else if (q == 20) s_sc[b][0]    = splus(a);
          else if (q < 41)  s_wk[b][q-21] = tanhf_(a);
          else if (q == 41) s_sc[b][1]    = splus(a);
          else if (q < 62)  s_er[b][q-42] = sigf(a);
          else if (q < 82)  s_wv[b][q-62] = tanhf_(a);
          else if (q == 82) s_sc[b][2]    = sigf(a);
          else if (q == 83) s_sc[b][3]    = sigf(a);
          else if (q == 84) s_sc[b][4]    = sigf(a);
          else              s_mraw[b][q-85] = a;
        }
      }
    } else {
      for (int e = (w-6)*64 + l; e < GB*NIN; e += 128) {
        int b = e/NIN, i = e - b*NIN;
        if (t+1 < NT) {
          float v = x[((size_t)(bbase+b)*NT + (t+1))*NIN + i];
          s_inpf[((i>>3)*16 + b)*8 + (i&7)] = (h1)v;
        }
      }
    }
    __syncthreads();   // B4: xi outputs ready for next step's DNC
  }

  // ---- final DNC for t = NT-1 ----
  dncH(); LDSFENCE();
  dncI(); LDSFENCE();
  dncJ(); LDSFENCE();
  dncK(); LDSFENCE();
  dncL(); LDSFENCE();
  dncM();
  __syncthreads();

  // ---- epilogue: y = [ctrl, rv] @ Wout^T + bout ----
  if (tid < GB*NOUT) {
    int b = tid & 15, o = tid >> 4;
    float a = bout[o];
    const float* Wr = Wout + o*(HID+CW);
    #pragma unroll 4
    for (int k = 0; k < HID; ++k) a += Wr[k]*s_ctrl32[b][k];
    #pragma unroll
    for (int c = 0; c < CW; ++c) a += Wr[HID+c]*s_rv[b][c];
    out[(size_t)(bbase+b)*NOUT + o] = a;
  }
#undef LDG
#undef MMAH0
#undef MMAH1
}

extern "C" void kernel_launch(void* const* d_in, const int* in_sizes, int n_in,
                              void* d_out, int out_size, void* d_ws, size_t ws_size,
                              hipStream_t stream) {
  (void)in_sizes; (void)n_in; (void)out_size; (void)ws_size;
  const float* x    = (const float*)d_in[0];
  const float* Wih0 = (const float*)d_in[1];
  const float* Whh0 = (const float*)d_in[2];
  const float* b0   = (const float*)d_in[3];
  const float* Wih1 = (const float*)d_in[4];
  const float* Whh1 = (const float*)d_in[5];
  const float* b1   = (const float*)d_in[6];
  const float* Wif  = (const float*)d_in[7];
  const float* bif  = (const float*)d_in[8];
  const float* Wout = (const float*)d_in[9];
  const float* bout = (const float*)d_in[10];
  float* out = (float*)d_out;
  float4* ws = (float4*)d_ws;

  dnc_packf_kernel<<<dim3(96), dim3(256), 0, stream>>>(Whh0, Wih1, Whh1, ws);
  dnc_olap2_kernel<<<dim3(NWG), dim3(BLK), 0, stream>>>(
      x, Wih0, Whh0, b0, Wih1, Whh1, b1, Wif, bif, Wout, bout, ws, out);
}